// Round 4
// baseline (4195.753 us; speedup 1.0000x reference)
//
#include <hip/hip_runtime.h>
#include <hip/hip_bf16.h>

// Problem constants (fp32 I/O; bf16 internally for MFMA)
#define LAT    256
#define HID    1024
#define TSTEPS 10
#define MTOT   16384            // 32*512 trajectory rows (corrcoef rows sliced away)
#define RPB    64               // rows per block
#define NBLK   (MTOT/RPB)       // 256 blocks = 1 per CU
#define CHUNK  512              // HIDDEN chunk held in LDS
#define NCHUNK 2
#define C2L2E  2.885390081777927f   // 2*log2(e): tanh(v) via exp2(C*v)

typedef short bf16x8 __attribute__((ext_vector_type(8)));
typedef float f32x4  __attribute__((ext_vector_type(4)));

// pack 4 f32 -> 4 bf16 (RNE via v_cvt_pk_bf16_f32) -> one ds_write_b64
__device__ __forceinline__ void st4bf(char* p, f32x4 v) {
    __hip_bfloat162 lo = __float22bfloat162_rn(make_float2(v[0], v[1]));
    __hip_bfloat162 hi = __float22bfloat162_rn(make_float2(v[2], v[3]));
    unsigned int ulo, uhi;
    __builtin_memcpy(&ulo, &lo, 4);
    __builtin_memcpy(&uhi, &hi, 4);
    unsigned long long u = (unsigned long long)ulo | ((unsigned long long)uhi << 32);
    *(unsigned long long*)p = u;
}

// XOR swizzles: spread 512B/1024B-strided rows across the 128B bank window.
__device__ __forceinline__ int addrX(int row, int kb) {   // Xs [64][256] bf16
    return row * 512 + (kb ^ ((row & 7) << 4));
}
__device__ __forceinline__ int addrH(int row, int kb) {   // Hc [64][512] bf16
    return row * 1024 + (kb ^ ((row & 7) << 4));
}

// ---- weight repack: src [K][N] f32  ->  dst fragment-linear bf16 tiles ----
// Tile (tn, tk) = 16 n-rows x 32 k-cols, lane-ordered: one wave fragment =
// one coalesced 1 KB burst, directly MFMA-A-operand shaped.
// dst[(tn*(K/32)+tk)*512 + (q*16+l16)*8 + j] = bf16(src[(tk*32+q*8+j)*N + tn*16+l16])
__global__ void pack_kernel(const float* __restrict__ src,
                            __hip_bfloat16* __restrict__ dst,
                            int N, int K) {
    int i = blockIdx.x * blockDim.x + threadIdx.x;
    if (i >= N * K) return;
    int KT   = K >> 5;
    int tile = i >> 9, wi = i & 511;
    int lane8 = wi >> 3, j = wi & 7;
    int q = lane8 >> 4, l16 = lane8 & 15;
    int tn = tile / KT, tk = tile - tn * KT;
    int n = tn * 16 + l16;
    int k = tk * 32 + q * 8 + j;
    dst[i] = __float2bfloat16(src[(size_t)k * N + n]);
}

// ---- persistent fused RK4 integrator ------------------------------------
// 256 blocks x 1024 threads (16 waves, 4/SIMD).
// Phase A (weight-minimal): wave owns hid cols [c*512 + wave*32, +32) for
//   ALL 64 traj ([2tn x 4nt]) -> each W1 fragment read by exactly one wave.
//   Bias enters as the MFMA C-initializer. tanh -> Hc[c] (full 64x512).
// Phase B: wtraj = wave&1 (32 traj), wgrp = wave>>1 owns lat [wgrp*32,+32)
//   ([2tn x 2nt]); kacc += W2 . Hc^T.
// Schedule/eval: A(0) | bar | B(0); A(1) | bar | B(1); RK4 | bar
//   -> 3 barriers, every interval mixes MFMA + LDS + VMEM + VALU.
__global__ __launch_bounds__(1024, 4)
void ode_kernel(const float* __restrict__ fp,
                const float* __restrict__ ts,
                const __hip_bfloat16* __restrict__ W1p,   // [HID/16][LAT/32] tiles
                const float* __restrict__ bias1,
                const __hip_bfloat16* __restrict__ W2p,   // [LAT/16][HID/32] tiles
                float* __restrict__ out) {
    __shared__ __align__(16) unsigned short Xs_s[64 * 256];      //  32 KB
    __shared__ __align__(16) unsigned short Hc_s[2][64 * 512];   // 128 KB
    char* XsB = (char*)Xs_s;

    const int tid   = threadIdx.x;
    const int lane  = tid & 63;
    const int wave  = tid >> 6;           // 0..15
    const int wtraj = wave & 1;           // phase-B / state traj group
    const int wgrp  = wave >> 1;          // 0..7: phase-B / state lat slice
    const int q = lane >> 4, l16 = lane & 15;
    const int grow0 = blockIdx.x * RPB;

    // State ownership (phase-B D-layout):
    //   traj = wtraj*32 + nt*16 + l16,  lat = wgrp*32 + mt*16 + q*4 + r
    f32x4 x_[2][2], ksum[2][2], kacc[2][2];

    // init: float4 state load, t=0 output slice, packed b64 Xs build
    #pragma unroll
    for (int mt = 0; mt < 2; ++mt) {
        #pragma unroll
        for (int nt = 0; nt < 2; ++nt) {
            const int traj = wtraj * 32 + nt * 16 + l16;
            const int lat  = wgrp * 32 + mt * 16 + q * 4;
            float4 v = *(const float4*)(fp + (size_t)(grow0 + traj) * LAT + lat);
            x_[mt][nt] = (f32x4){v.x, v.y, v.z, v.w};
            *(float4*)(out + ((size_t)(grow0 + traj) * TSTEPS) * LAT + lat) = v;
            st4bf(XsB + addrX(traj, lat * 2), x_[mt][nt]);
        }
    }
    __syncthreads();

    // phase A: a1 = bias + W1 . Xs^T for chunk c; tanh -> Hc
    auto phaseA = [&](int c, char* HcB) {
        f32x4 a1[2][4];
        #pragma unroll
        for (int mt = 0; mt < 2; ++mt) {
            f32x4 bb = *(const f32x4*)(bias1 + c * CHUNK + wave * 32 + mt * 16 + q * 4);
            #pragma unroll
            for (int nt = 0; nt < 4; ++nt) a1[mt][nt] = bb;
        }
        #pragma unroll
        for (int kk = 0; kk < 8; ++kk) {
            bf16x8 xf[4];
            #pragma unroll
            for (int nt = 0; nt < 4; ++nt)
                xf[nt] = *(const bf16x8*)(XsB + addrX(nt * 16 + l16, kk * 64 + q * 16));
            #pragma unroll
            for (int mt = 0; mt < 2; ++mt) {
                bf16x8 wf = *(const bf16x8*)(W1p +
                    (size_t)((c * 32 + wave * 2 + mt) * 8 + kk) * 512 + lane * 8);
                #pragma unroll
                for (int nt = 0; nt < 4; ++nt)
                    a1[mt][nt] = __builtin_amdgcn_mfma_f32_16x16x32_bf16(
                                     wf, xf[nt], a1[mt][nt], 0, 0, 0);
            }
        }
        #pragma unroll
        for (int mt = 0; mt < 2; ++mt) {
            #pragma unroll
            for (int nt = 0; nt < 4; ++nt) {
                f32x4 th;
                #pragma unroll
                for (int r = 0; r < 4; ++r) {
                    float e  = __builtin_amdgcn_exp2f(a1[mt][nt][r] * C2L2E);
                    float rc = __builtin_amdgcn_rcpf(e + 1.f);
                    th[r] = fmaf(-2.f, rc, 1.f);            // tanh
                }
                st4bf(HcB + addrH(nt * 16 + l16, wave * 64 + mt * 32 + q * 8), th);
            }
        }
    };

    // phase B: kacc += W2 . Hc^T for chunk c
    auto phaseB = [&](int c, const char* HcB) {
        #pragma unroll
        for (int kk = 0; kk < 16; ++kk) {
            bf16x8 hf[2];
            #pragma unroll
            for (int nt = 0; nt < 2; ++nt)
                hf[nt] = *(const bf16x8*)(HcB +
                    addrH(wtraj * 32 + nt * 16 + l16, kk * 64 + q * 16));
            #pragma unroll
            for (int mt = 0; mt < 2; ++mt) {
                bf16x8 wf = *(const bf16x8*)(W2p +
                    (size_t)((wgrp * 2 + mt) * 32 + c * 16 + kk) * 512 + lane * 8);
                kacc[mt][0] = __builtin_amdgcn_mfma_f32_16x16x32_bf16(wf, hf[0], kacc[mt][0], 0, 0, 0);
                kacc[mt][1] = __builtin_amdgcn_mfma_f32_16x16x32_bf16(wf, hf[1], kacc[mt][1], 0, 0, 0);
            }
        }
    };

    #pragma unroll 1
    for (int step = 0; step < TSTEPS - 1; ++step) {
        const float dt = ts[step + 1] - ts[step];

        #pragma unroll 1
        for (int s = 0; s < 4; ++s) {
            #pragma unroll
            for (int mt = 0; mt < 2; ++mt) {
                kacc[mt][0] = (f32x4){0.f, 0.f, 0.f, 0.f};
                kacc[mt][1] = (f32x4){0.f, 0.f, 0.f, 0.f};
            }

            phaseA(0, (char*)Hc_s[0]);
            __syncthreads();                 // Hc[0] ready
            phaseB(0, (const char*)Hc_s[0]);
            phaseA(1, (char*)Hc_s[1]);
            __syncthreads();                 // Hc[1] ready
            phaseB(1, (const char*)Hc_s[1]);

            // ---------------- RK4 combine + next stage input ----------------
            if (s < 3) {
                const float cw = (s == 2) ? dt : 0.5f * dt;
                #pragma unroll
                for (int mt = 0; mt < 2; ++mt) {
                    #pragma unroll
                    for (int nt = 0; nt < 2; ++nt) {
                        if (s == 0) ksum[mt][nt] = kacc[mt][nt];
                        else        ksum[mt][nt] += 2.f * kacc[mt][nt];
                        const int traj = wtraj * 32 + nt * 16 + l16;
                        const int lat  = wgrp * 32 + mt * 16 + q * 4;
                        f32x4 xv = x_[mt][nt] + cw * kacc[mt][nt];
                        st4bf(XsB + addrX(traj, lat * 2), xv);
                    }
                }
            } else {
                const float d6 = dt * (1.f / 6.f);
                #pragma unroll
                for (int mt = 0; mt < 2; ++mt) {
                    #pragma unroll
                    for (int nt = 0; nt < 2; ++nt) {
                        const int traj = wtraj * 32 + nt * 16 + l16;
                        const int lat  = wgrp * 32 + mt * 16 + q * 4;
                        f32x4 xv = x_[mt][nt] + d6 * (ksum[mt][nt] + kacc[mt][nt]);
                        x_[mt][nt] = xv;
                        st4bf(XsB + addrX(traj, lat * 2), xv);
                        *(float4*)(out + ((size_t)(grow0 + traj) * TSTEPS + (step + 1)) * LAT + lat)
                            = make_float4(xv[0], xv[1], xv[2], xv[3]);
                    }
                }
            }
            __syncthreads();   // Xs ready; Hc[0]/Hc[1] free for next eval
        }
    }
}

extern "C" void kernel_launch(void* const* d_in, const int* in_sizes, int n_in,
                              void* d_out, int out_size, void* d_ws, size_t ws_size,
                              hipStream_t stream) {
    (void)in_sizes; (void)n_in; (void)out_size; (void)ws_size;
    const float* fp = (const float*)d_in[0];
    const float* ts = (const float*)d_in[1];
    const float* W1 = (const float*)d_in[2];
    const float* b1 = (const float*)d_in[3];
    const float* W2 = (const float*)d_in[4];
    float* out = (float*)d_out;

    __hip_bfloat16* W1p = (__hip_bfloat16*)d_ws;                 // 512 KB
    __hip_bfloat16* W2p = W1p + (size_t)HID * LAT;               // 512 KB

    // W1: n-dim = HID, k-dim = LAT; src W1 is [LAT][HID] = [K][N]
    pack_kernel<<<(HID * LAT) / 256, 256, 0, stream>>>(W1, W1p, HID, LAT);
    // W2: n-dim = LAT, k-dim = HID; src W2 is [HID][LAT] = [K][N]
    pack_kernel<<<(HID * LAT) / 256, 256, 0, stream>>>(W2, W2p, LAT, HID);

    ode_kernel<<<NBLK, 1024, 0, stream>>>(fp, ts, W1p, b1, W2p, out);
}

// Round 5
// 2355.036 us; speedup vs baseline: 1.7816x; 1.7816x over previous
//
#include <hip/hip_runtime.h>
#include <hip/hip_bf16.h>

// Problem constants (fp32 I/O; bf16 internally for MFMA)
#define LAT    256
#define HID    1024
#define TSTEPS 10
#define MTOT   16384            // 32*512 trajectory rows (corrcoef rows sliced away)
#define RPB    64               // rows per block
#define NBLK   (MTOT/RPB)       // 256 blocks = 1 per CU
#define C2L2E  2.885390081777927f   // 2*log2(e): tanh(v) via exp2(C*v)

typedef short bf16x8 __attribute__((ext_vector_type(8)));
typedef float f32x4  __attribute__((ext_vector_type(4)));

// pack 4 f32 -> 4 bf16 (RNE via v_cvt_pk_bf16_f32) -> one ds_write_b64
__device__ __forceinline__ void st4bf(char* p, f32x4 v) {
    __hip_bfloat162 lo = __float22bfloat162_rn(make_float2(v[0], v[1]));
    __hip_bfloat162 hi = __float22bfloat162_rn(make_float2(v[2], v[3]));
    unsigned int ulo, uhi;
    __builtin_memcpy(&ulo, &lo, 4);
    __builtin_memcpy(&uhi, &hi, 4);
    unsigned long long u = (unsigned long long)ulo | ((unsigned long long)uhi << 32);
    *(unsigned long long*)p = u;
}

// XOR swizzles: spread power-of-2-strided rows across the 128B bank window.
__device__ __forceinline__ int addrX(int row, int kb) {   // Xs [64][256] bf16
    return row * 512 + (kb ^ ((row & 7) << 4));
}
__device__ __forceinline__ int addrH(int row, int kb) {   // Hc [64][1024] bf16
    return row * 2048 + (kb ^ ((row & 7) << 4));
}

// ---- weight repack: src [K][N] f32  ->  dst fragment-linear bf16 tiles ----
// Tile (tn, tk) = 16 n-rows x 32 k-cols, lane-ordered: one wave fragment =
// one coalesced 1 KB burst, directly MFMA-A-operand shaped.
// dst[(tn*(K/32)+tk)*512 + (q*16+l16)*8 + j] = bf16(src[(tk*32+q*8+j)*N + tn*16+l16])
__global__ void pack_kernel(const float* __restrict__ src,
                            __hip_bfloat16* __restrict__ dst,
                            int N, int K) {
    int i = blockIdx.x * blockDim.x + threadIdx.x;
    if (i >= N * K) return;
    int KT   = K >> 5;
    int tile = i >> 9, wi = i & 511;
    int lane8 = wi >> 3, j = wi & 7;
    int q = lane8 >> 4, l16 = lane8 & 15;
    int tn = tile / KT, tk = tile - tn * KT;
    int n = tn * 16 + l16;
    int k = tk * 32 + q * 8 + j;
    dst[i] = __float2bfloat16(src[(size_t)k * N + n]);
}

// ---- persistent fused RK4 integrator ------------------------------------
// 256 blocks x 1024 threads (16 waves, 4/SIMD). LDS = 160 KB exactly.
// Phase A (weight-minimal): wave owns hid [wave*64,+64) for ALL 64 traj,
//   as two register-light passes of a1[2mt][4nt] (32 VGPR). Each W1 fragment
//   is read by exactly one wave (512 KB/CU/eval). Bias enters as MFMA C-init.
//   tanh -> Hc[64 traj][1024 hid] (single buffer: hid slices are disjoint).
// Phase B: wtraj = wave&1 (32 traj), wgrp = wave>>1 owns lat [wgrp*32,+32);
//   kacc[2][2] += W2 . Hc^T over full K=1024.
// Schedule/eval: A | bar | B; RK4 | bar   -> 2 barriers total.
//   Hazards: next A writes Hc only after bar2 (B read it before bar2); RK4
//   writes Xs after bar1 (A read it before bar1); next A reads Xs after bar2.
__global__ __launch_bounds__(1024, 1)
void ode_kernel(const float* __restrict__ fp,
                const float* __restrict__ ts,
                const __hip_bfloat16* __restrict__ W1p,   // [HID/16][LAT/32] tiles
                const float* __restrict__ bias1,
                const __hip_bfloat16* __restrict__ W2p,   // [LAT/16][HID/32] tiles
                float* __restrict__ out) {
    __shared__ __align__(16) unsigned short Xs_s[64 * 256];    //  32 KB
    __shared__ __align__(16) unsigned short Hc_s[64 * 1024];   // 128 KB
    char* XsB = (char*)Xs_s;
    char* HcB = (char*)Hc_s;

    const int tid   = threadIdx.x;
    const int lane  = tid & 63;
    const int wave  = tid >> 6;           // 0..15
    const int wtraj = wave & 1;           // phase-B / state traj group
    const int wgrp  = wave >> 1;          // 0..7: phase-B / state lat slice
    const int q = lane >> 4, l16 = lane & 15;
    const int grow0 = blockIdx.x * RPB;

    // State ownership (phase-B D-layout):
    //   traj = wtraj*32 + nt*16 + l16,  lat = wgrp*32 + mt*16 + q*4 + r
    f32x4 x_[2][2], ksum[2][2], kacc[2][2];

    // init: float4 state load, t=0 output slice, packed b64 Xs build
    #pragma unroll
    for (int mt = 0; mt < 2; ++mt) {
        #pragma unroll
        for (int nt = 0; nt < 2; ++nt) {
            const int traj = wtraj * 32 + nt * 16 + l16;
            const int lat  = wgrp * 32 + mt * 16 + q * 4;
            float4 v = *(const float4*)(fp + (size_t)(grow0 + traj) * LAT + lat);
            x_[mt][nt] = (f32x4){v.x, v.y, v.z, v.w};
            *(float4*)(out + ((size_t)(grow0 + traj) * TSTEPS) * LAT + lat) = v;
            st4bf(XsB + addrX(traj, lat * 2), x_[mt][nt]);
        }
    }
    __syncthreads();

    #pragma unroll 1
    for (int step = 0; step < TSTEPS - 1; ++step) {
        const float dt = ts[step + 1] - ts[step];

        #pragma unroll 1
        for (int s = 0; s < 4; ++s) {
            // ================= phase A: Hc = tanh(W1 . Xs^T + b) ==========
            #pragma unroll 1
            for (int h2 = 0; h2 < 2; ++h2) {
                const int hidb = wave * 64 + h2 * 32;      // wave's 32-hid slice
                f32x4 a1[2][4];
                #pragma unroll
                for (int mt = 0; mt < 2; ++mt) {
                    f32x4 bb = *(const f32x4*)(bias1 + hidb + mt * 16 + q * 4);
                    #pragma unroll
                    for (int nt = 0; nt < 4; ++nt) a1[mt][nt] = bb;
                }
                #pragma unroll
                for (int kk = 0; kk < 8; ++kk) {
                    bf16x8 xf[4];
                    #pragma unroll
                    for (int nt = 0; nt < 4; ++nt)
                        xf[nt] = *(const bf16x8*)(XsB +
                            addrX(nt * 16 + l16, kk * 64 + q * 16));
                    #pragma unroll
                    for (int mt = 0; mt < 2; ++mt) {
                        bf16x8 wf = *(const bf16x8*)(W1p +
                            (size_t)(((hidb >> 4) + mt) * 8 + kk) * 512 + lane * 8);
                        #pragma unroll
                        for (int nt = 0; nt < 4; ++nt)
                            a1[mt][nt] = __builtin_amdgcn_mfma_f32_16x16x32_bf16(
                                             wf, xf[nt], a1[mt][nt], 0, 0, 0);
                    }
                }
                #pragma unroll
                for (int mt = 0; mt < 2; ++mt) {
                    #pragma unroll
                    for (int nt = 0; nt < 4; ++nt) {
                        f32x4 th;
                        #pragma unroll
                        for (int r = 0; r < 4; ++r) {
                            float e  = __builtin_amdgcn_exp2f(a1[mt][nt][r] * C2L2E);
                            float rc = __builtin_amdgcn_rcpf(e + 1.f);
                            th[r] = fmaf(-2.f, rc, 1.f);            // tanh
                        }
                        st4bf(HcB + addrH(nt * 16 + l16,
                                          (hidb + mt * 16 + q * 4) * 2), th);
                    }
                }
            }
            __syncthreads();                // Hc fully written

            // ================= phase B: kacc = W2 . Hc^T ==================
            #pragma unroll
            for (int mt = 0; mt < 2; ++mt) {
                kacc[mt][0] = (f32x4){0.f, 0.f, 0.f, 0.f};
                kacc[mt][1] = (f32x4){0.f, 0.f, 0.f, 0.f};
            }
            #pragma unroll 8
            for (int kk = 0; kk < 32; ++kk) {
                bf16x8 hf[2];
                #pragma unroll
                for (int nt = 0; nt < 2; ++nt)
                    hf[nt] = *(const bf16x8*)(HcB +
                        addrH(wtraj * 32 + nt * 16 + l16, kk * 64 + q * 16));
                #pragma unroll
                for (int mt = 0; mt < 2; ++mt) {
                    bf16x8 wf = *(const bf16x8*)(W2p +
                        (size_t)((wgrp * 2 + mt) * 32 + kk) * 512 + lane * 8);
                    kacc[mt][0] = __builtin_amdgcn_mfma_f32_16x16x32_bf16(wf, hf[0], kacc[mt][0], 0, 0, 0);
                    kacc[mt][1] = __builtin_amdgcn_mfma_f32_16x16x32_bf16(wf, hf[1], kacc[mt][1], 0, 0, 0);
                }
            }

            // ---------------- RK4 combine + next stage input ----------------
            if (s < 3) {
                const float cw = (s == 2) ? dt : 0.5f * dt;
                #pragma unroll
                for (int mt = 0; mt < 2; ++mt) {
                    #pragma unroll
                    for (int nt = 0; nt < 2; ++nt) {
                        if (s == 0) ksum[mt][nt] = kacc[mt][nt];
                        else        ksum[mt][nt] += 2.f * kacc[mt][nt];
                        const int traj = wtraj * 32 + nt * 16 + l16;
                        const int lat  = wgrp * 32 + mt * 16 + q * 4;
                        f32x4 xv = x_[mt][nt] + cw * kacc[mt][nt];
                        st4bf(XsB + addrX(traj, lat * 2), xv);
                    }
                }
            } else {
                const float d6 = dt * (1.f / 6.f);
                #pragma unroll
                for (int mt = 0; mt < 2; ++mt) {
                    #pragma unroll
                    for (int nt = 0; nt < 2; ++nt) {
                        const int traj = wtraj * 32 + nt * 16 + l16;
                        const int lat  = wgrp * 32 + mt * 16 + q * 4;
                        f32x4 xv = x_[mt][nt] + d6 * (ksum[mt][nt] + kacc[mt][nt]);
                        x_[mt][nt] = xv;
                        st4bf(XsB + addrX(traj, lat * 2), xv);
                        *(float4*)(out + ((size_t)(grow0 + traj) * TSTEPS + (step + 1)) * LAT + lat)
                            = make_float4(xv[0], xv[1], xv[2], xv[3]);
                    }
                }
            }
            __syncthreads();   // Xs ready; Hc free for next eval's phase A
        }
    }
}

extern "C" void kernel_launch(void* const* d_in, const int* in_sizes, int n_in,
                              void* d_out, int out_size, void* d_ws, size_t ws_size,
                              hipStream_t stream) {
    (void)in_sizes; (void)n_in; (void)out_size; (void)ws_size;
    const float* fp = (const float*)d_in[0];
    const float* ts = (const float*)d_in[1];
    const float* W1 = (const float*)d_in[2];
    const float* b1 = (const float*)d_in[3];
    const float* W2 = (const float*)d_in[4];
    float* out = (float*)d_out;

    __hip_bfloat16* W1p = (__hip_bfloat16*)d_ws;                 // 512 KB
    __hip_bfloat16* W2p = W1p + (size_t)HID * LAT;               // 512 KB

    // W1: n-dim = HID, k-dim = LAT; src W1 is [LAT][HID] = [K][N]
    pack_kernel<<<(HID * LAT) / 256, 256, 0, stream>>>(W1, W1p, HID, LAT);
    // W2: n-dim = LAT, k-dim = HID; src W2 is [HID][LAT] = [K][N]
    pack_kernel<<<(HID * LAT) / 256, 256, 0, stream>>>(W2, W2p, LAT, HID);

    ode_kernel<<<NBLK, 1024, 0, stream>>>(fp, ts, W1p, b1, W2p, out);
}

// Round 6
// 2287.850 us; speedup vs baseline: 1.8339x; 1.0294x over previous
//
#include <hip/hip_runtime.h>
#include <hip/hip_bf16.h>

// Problem constants (fp32 I/O; bf16 internally for MFMA)
#define LAT    256
#define HID    1024
#define TSTEPS 10
#define MTOT   16384            // 32*512 trajectory rows (corrcoef rows sliced away)
#define RPB    64               // rows per block
#define NBLK   (MTOT/RPB)       // 256 blocks = 1 per CU
#define C2L2E  2.885390081777927f   // 2*log2(e): tanh(v) via exp2(C*v)

typedef short bf16x8 __attribute__((ext_vector_type(8)));
typedef float f32x4  __attribute__((ext_vector_type(4)));

// pack 4 f32 -> 4 bf16 (RNE via v_cvt_pk_bf16_f32) -> one ds_write_b64
__device__ __forceinline__ void st4bf(char* p, f32x4 v) {
    __hip_bfloat162 lo = __float22bfloat162_rn(make_float2(v[0], v[1]));
    __hip_bfloat162 hi = __float22bfloat162_rn(make_float2(v[2], v[3]));
    unsigned int ulo, uhi;
    __builtin_memcpy(&ulo, &lo, 4);
    __builtin_memcpy(&uhi, &hi, 4);
    unsigned long long u = (unsigned long long)ulo | ((unsigned long long)uhi << 32);
    *(unsigned long long*)p = u;
}

// XOR swizzles: spread power-of-2-strided rows across the 128B bank window.
__device__ __forceinline__ int addrX(int row, int kb) {   // Xs [64][256] bf16
    return row * 512 + (kb ^ ((row & 7) << 4));
}
__device__ __forceinline__ int addrH(int row, int kb) {   // Hc [64][1024] bf16
    return row * 2048 + (kb ^ ((row & 7) << 4));
}

// ---- weight repack: src [K][N] f32  ->  dst fragment-linear bf16 tiles ----
// Tile (tn, tk) = 16 n-rows x 32 k-cols, lane-ordered: one wave fragment =
// one coalesced 1 KB burst, directly MFMA-A-operand shaped.
// dst[(tn*(K/32)+tk)*512 + (q*16+l16)*8 + j] = bf16(src[(tk*32+q*8+j)*N + tn*16+l16])
__global__ void pack_kernel(const float* __restrict__ src,
                            __hip_bfloat16* __restrict__ dst,
                            int N, int K) {
    int i = blockIdx.x * blockDim.x + threadIdx.x;
    if (i >= N * K) return;
    int KT   = K >> 5;
    int tile = i >> 9, wi = i & 511;
    int lane8 = wi >> 3, j = wi & 7;
    int q = lane8 >> 4, l16 = lane8 & 15;
    int tn = tile / KT, tk = tile - tn * KT;
    int n = tn * 16 + l16;
    int k = tk * 32 + q * 8 + j;
    dst[i] = __float2bfloat16(src[(size_t)k * N + n]);
}

// ---- persistent fused RK4 integrator ------------------------------------
// 256 blocks x 1024 threads (16 waves, 4/SIMD). LDS = 160 KB exactly.
// REGISTER PLAN (the round-4/5 failure was spills at the 64-VGPR budget):
//   - NO persistent f32 state in registers. x == out[:,step,:] (same thread
//     wrote it) -> reload at combine. ksum lives in global acc_g (private
//     per-thread addresses, L2-resident, touched only at combines).
//   - a1 / kacc are pure MFMA C/D chains -> AGPRs (32 + 16 <= 64).
//   - Phase live set: fragments + addresses ~50 VGPR.
//   - amdgpu_waves_per_eu(4,4) states the true occupancy (LDS-pinned) so
//     the allocator budgets 128 regs instead of 64.
// Phase A (weight-minimal): wave owns hid [wave*64,+64) for ALL 64 traj,
//   two passes of a1[2mt][4nt]; each W1 fragment read by exactly one wave.
//   Bias enters as MFMA C-init. tanh -> Hc[64][1024] (single buffer).
// Phase B: wtraj = wave&1 (32 traj), wgrp = wave>>1 owns lat [wgrp*32,+32);
//   kacc[2][2] += W2 . Hc^T over K=1024.
// Schedule/eval: A | bar | B; combine | bar   -> 2 barriers.
__global__ __attribute__((amdgpu_waves_per_eu(4, 4))) __launch_bounds__(1024)
void ode_kernel(const float* __restrict__ fp,
                const float* __restrict__ ts,
                const __hip_bfloat16* __restrict__ W1p,   // [HID/16][LAT/32] tiles
                const float* __restrict__ bias1,
                const __hip_bfloat16* __restrict__ W2p,   // [LAT/16][HID/32] tiles
                float* __restrict__ acc_g,                // [MTOT][LAT] ksum ws
                float* __restrict__ out) {
    __shared__ __align__(16) unsigned short Xs_s[64 * 256];    //  32 KB
    __shared__ __align__(16) unsigned short Hc_s[64 * 1024];   // 128 KB
    char* XsB = (char*)Xs_s;
    char* HcB = (char*)Hc_s;

    const int tid   = threadIdx.x;
    const int lane  = tid & 63;
    const int wave  = tid >> 6;           // 0..15
    const int wtraj = wave & 1;           // phase-B / state traj group
    const int wgrp  = wave >> 1;          // 0..7: phase-B / state lat slice
    const int q = lane >> 4, l16 = lane & 15;
    const int grow0 = blockIdx.x * RPB;

    // init: t=0 out slice + Xs build (no register state kept)
    #pragma unroll
    for (int mt = 0; mt < 2; ++mt) {
        #pragma unroll
        for (int nt = 0; nt < 2; ++nt) {
            const int traj = wtraj * 32 + nt * 16 + l16;
            const int lat  = wgrp * 32 + mt * 16 + q * 4;
            float4 v = *(const float4*)(fp + (size_t)(grow0 + traj) * LAT + lat);
            *(float4*)(out + ((size_t)(grow0 + traj) * TSTEPS) * LAT + lat) = v;
            st4bf(XsB + addrX(traj, lat * 2), (f32x4){v.x, v.y, v.z, v.w});
        }
    }
    __syncthreads();

    #pragma unroll 1
    for (int step = 0; step < TSTEPS - 1; ++step) {
        const float dt = ts[step + 1] - ts[step];

        #pragma unroll 1
        for (int s = 0; s < 4; ++s) {
            // ================= phase A: Hc = tanh(W1 . Xs^T + b) ==========
            #pragma unroll 1
            for (int h2 = 0; h2 < 2; ++h2) {
                const int hidb = wave * 64 + h2 * 32;      // wave's 32-hid slice
                f32x4 a1[2][4];
                #pragma unroll
                for (int mt = 0; mt < 2; ++mt) {
                    float4 b4 = *(const float4*)(bias1 + hidb + mt * 16 + q * 4);
                    f32x4 bb = (f32x4){b4.x, b4.y, b4.z, b4.w};
                    #pragma unroll
                    for (int nt = 0; nt < 4; ++nt) a1[mt][nt] = bb;
                }
                #pragma unroll
                for (int kk = 0; kk < 8; ++kk) {
                    bf16x8 xf[4];
                    #pragma unroll
                    for (int nt = 0; nt < 4; ++nt)
                        xf[nt] = *(const bf16x8*)(XsB +
                            addrX(nt * 16 + l16, kk * 64 + q * 16));
                    #pragma unroll
                    for (int mt = 0; mt < 2; ++mt) {
                        bf16x8 wf = *(const bf16x8*)(W1p +
                            (size_t)(((hidb >> 4) + mt) * 8 + kk) * 512 + lane * 8);
                        #pragma unroll
                        for (int nt = 0; nt < 4; ++nt)
                            a1[mt][nt] = __builtin_amdgcn_mfma_f32_16x16x32_bf16(
                                             wf, xf[nt], a1[mt][nt], 0, 0, 0);
                    }
                }
                #pragma unroll
                for (int mt = 0; mt < 2; ++mt) {
                    #pragma unroll
                    for (int nt = 0; nt < 4; ++nt) {
                        f32x4 th;
                        #pragma unroll
                        for (int r = 0; r < 4; ++r) {
                            float e  = __builtin_amdgcn_exp2f(a1[mt][nt][r] * C2L2E);
                            float rc = __builtin_amdgcn_rcpf(e + 1.f);
                            th[r] = fmaf(-2.f, rc, 1.f);            // tanh
                        }
                        st4bf(HcB + addrH(nt * 16 + l16,
                                          (hidb + mt * 16 + q * 4) * 2), th);
                    }
                }
            }
            __syncthreads();                // Hc fully written

            // ================= phase B: kacc = W2 . Hc^T ==================
            f32x4 kacc[2][2];
            #pragma unroll
            for (int mt = 0; mt < 2; ++mt) {
                kacc[mt][0] = (f32x4){0.f, 0.f, 0.f, 0.f};
                kacc[mt][1] = (f32x4){0.f, 0.f, 0.f, 0.f};
            }
            #pragma unroll 8
            for (int kk = 0; kk < 32; ++kk) {
                bf16x8 hf[2];
                #pragma unroll
                for (int nt = 0; nt < 2; ++nt)
                    hf[nt] = *(const bf16x8*)(HcB +
                        addrH(wtraj * 32 + nt * 16 + l16, kk * 64 + q * 16));
                #pragma unroll
                for (int mt = 0; mt < 2; ++mt) {
                    bf16x8 wf = *(const bf16x8*)(W2p +
                        (size_t)((wgrp * 2 + mt) * 32 + kk) * 512 + lane * 8);
                    kacc[mt][0] = __builtin_amdgcn_mfma_f32_16x16x32_bf16(wf, hf[0], kacc[mt][0], 0, 0, 0);
                    kacc[mt][1] = __builtin_amdgcn_mfma_f32_16x16x32_bf16(wf, hf[1], kacc[mt][1], 0, 0, 0);
                }
            }

            // ------- RK4 combine: x from out[:,step,:], ksum in acc_g -------
            #pragma unroll
            for (int mt = 0; mt < 2; ++mt) {
                #pragma unroll
                for (int nt = 0; nt < 2; ++nt) {
                    const int traj = wtraj * 32 + nt * 16 + l16;
                    const int lat  = wgrp * 32 + mt * 16 + q * 4;
                    const size_t rowT = (size_t)(grow0 + traj) * TSTEPS;
                    float* accp = acc_g + (size_t)(grow0 + traj) * LAT + lat;
                    float4 x4 = *(const float4*)(out + (rowT + step) * LAT + lat);
                    f32x4 x  = (f32x4){x4.x, x4.y, x4.z, x4.w};
                    f32x4 kv = kacc[mt][nt];
                    if (s == 0) {
                        *(float4*)accp = make_float4(kv[0], kv[1], kv[2], kv[3]);
                        f32x4 xv = x + (0.5f * dt) * kv;
                        st4bf(XsB + addrX(traj, lat * 2), xv);
                    } else if (s < 3) {
                        const float cw = (s == 2) ? dt : 0.5f * dt;
                        float4 a4 = *(const float4*)accp;
                        *(float4*)accp = make_float4(fmaf(2.f, kv[0], a4.x),
                                                     fmaf(2.f, kv[1], a4.y),
                                                     fmaf(2.f, kv[2], a4.z),
                                                     fmaf(2.f, kv[3], a4.w));
                        f32x4 xv = x + cw * kv;
                        st4bf(XsB + addrX(traj, lat * 2), xv);
                    } else {
                        const float d6 = dt * (1.f / 6.f);
                        float4 a4 = *(const float4*)accp;
                        f32x4 av = (f32x4){a4.x, a4.y, a4.z, a4.w};
                        f32x4 xn = x + d6 * (av + kv);
                        st4bf(XsB + addrX(traj, lat * 2), xn);
                        *(float4*)(out + (rowT + step + 1) * LAT + lat)
                            = make_float4(xn[0], xn[1], xn[2], xn[3]);
                    }
                }
            }
            __syncthreads();   // Xs ready; Hc free for next eval's phase A
        }
    }
}

extern "C" void kernel_launch(void* const* d_in, const int* in_sizes, int n_in,
                              void* d_out, int out_size, void* d_ws, size_t ws_size,
                              hipStream_t stream) {
    (void)in_sizes; (void)n_in; (void)out_size; (void)ws_size;
    const float* fp = (const float*)d_in[0];
    const float* ts = (const float*)d_in[1];
    const float* W1 = (const float*)d_in[2];
    const float* b1 = (const float*)d_in[3];
    const float* W2 = (const float*)d_in[4];
    float* out = (float*)d_out;

    char* ws = (char*)d_ws;
    __hip_bfloat16* W1p = (__hip_bfloat16*)ws;                       // 512 KB
    __hip_bfloat16* W2p = (__hip_bfloat16*)(ws + (size_t)512 * 1024);// 512 KB
    float*          acc = (float*)(ws + (size_t)1024 * 1024);        // 16.8 MB

    // W1: n-dim = HID, k-dim = LAT; src W1 is [LAT][HID] = [K][N]
    pack_kernel<<<(HID * LAT) / 256, 256, 0, stream>>>(W1, W1p, HID, LAT);
    // W2: n-dim = LAT, k-dim = HID; src W2 is [HID][LAT] = [K][N]
    pack_kernel<<<(HID * LAT) / 256, 256, 0, stream>>>(W2, W2p, LAT, HID);

    ode_kernel<<<NBLK, 1024, 0, stream>>>(fp, ts, W1p, b1, W2p, acc, out);
}

// Round 7
// 2239.091 us; speedup vs baseline: 1.8739x; 1.0218x over previous
//
#include <hip/hip_runtime.h>
#include <hip/hip_bf16.h>

// Problem constants (fp32 I/O; bf16 internally for MFMA)
#define LAT    256
#define HID    1024
#define TSTEPS 10
#define MTOT   16384            // 32*512 trajectory rows (corrcoef rows sliced away)
#define RPB    64               // rows per block
#define NBLK   (MTOT/RPB)       // 256 blocks = 1 per CU
#define C2L2E  2.885390081777927f   // 2*log2(e): tanh(v) via exp2(C*v)

typedef short bf16x8 __attribute__((ext_vector_type(8)));
typedef float f32x4  __attribute__((ext_vector_type(4)));

// pack 4 f32 -> 4 bf16 (RNE via v_cvt_pk_bf16_f32) -> one ds_write_b64
__device__ __forceinline__ void st4bf(char* p, f32x4 v) {
    __hip_bfloat162 lo = __float22bfloat162_rn(make_float2(v[0], v[1]));
    __hip_bfloat162 hi = __float22bfloat162_rn(make_float2(v[2], v[3]));
    unsigned int ulo, uhi;
    __builtin_memcpy(&ulo, &lo, 4);
    __builtin_memcpy(&uhi, &hi, 4);
    unsigned long long u = (unsigned long long)ulo | ((unsigned long long)uhi << 32);
    *(unsigned long long*)p = u;
}

// XOR swizzles. 4 row bits (not 3): the b128 read pattern aliases lanes at
// (q ^ row_low); with 3 bits rows r and r+8 collide -> 8 lanes per 4-bank
// group (8-way, ~2.9x). 4 bits -> 4 lanes per group (~1.6x).
__device__ __forceinline__ int addrX(int row, int kb) {   // Xs [64][256] bf16
    return row * 512 + (kb ^ ((row & 15) << 4));
}
__device__ __forceinline__ int addrH(int row, int kb) {   // Hc [64][1024] bf16
    return row * 2048 + (kb ^ ((row & 15) << 4));
}

// ---- weight repack: src [K][N] f32  ->  dst fragment-linear bf16 tiles ----
// Tile (tn, tk) = 16 n-rows x 32 k-cols, lane-ordered: one wave fragment =
// one coalesced 1 KB burst, directly MFMA-A-operand shaped.
// dst[(tn*(K/32)+tk)*512 + (q*16+l16)*8 + j] = bf16(src[(tk*32+q*8+j)*N + tn*16+l16])
__global__ void pack_kernel(const float* __restrict__ src,
                            __hip_bfloat16* __restrict__ dst,
                            int N, int K) {
    int i = blockIdx.x * blockDim.x + threadIdx.x;
    if (i >= N * K) return;
    int KT   = K >> 5;
    int tile = i >> 9, wi = i & 511;
    int lane8 = wi >> 3, j = wi & 7;
    int q = lane8 >> 4, l16 = lane8 & 15;
    int tn = tile / KT, tk = tile - tn * KT;
    int n = tn * 16 + l16;
    int k = tk * 32 + q * 8 + j;
    dst[i] = __float2bfloat16(src[(size_t)k * N + n]);
}

// ---- persistent fused RK4 integrator ------------------------------------
// 256 blocks x 1024 threads (16 waves, 4/SIMD). LDS = 160 KB exactly.
// REGISTER PLAN: at 1024 threads the compiler pins 64 arch VGPRs (measured
// rounds 3-6); rounds 4-6 spilled at ~68 live. This version caps worst-case
// live at ~56: phase A holds only wf[2]+xf[2] fragments at once (a1[2][4]
// accumulators are MFMA C/D chains -> AGPR-eligible; fits even if not).
// No persistent f32 state: x == out[:,step,:] (same thread wrote it); ksum
// lives in acc_g (private addresses, L2/L3-resident, combines only).
// Phase A (weight-minimal): wave owns hid [wave*64,+64) for ALL 64 traj,
//   two h2-passes of a1[2mt][4nt]; each W1 fragment read by exactly one
//   wave (512 KB/CU/eval). Bias enters as MFMA C-init. tanh -> Hc[64][1024].
// Phase B: wtraj = wave&1 (32 traj), wgrp = wave>>1 owns lat [wgrp*32,+32);
//   kacc[2][2] += W2 . Hc^T over K=1024 (W2: 1 MB/CU/eval).
// Schedule/eval: A | bar | B; combine | bar   -> 2 barriers.
__global__ __launch_bounds__(1024, 4)
void ode_kernel(const float* __restrict__ fp,
                const float* __restrict__ ts,
                const __hip_bfloat16* __restrict__ W1p,   // [HID/16][LAT/32] tiles
                const float* __restrict__ bias1,
                const __hip_bfloat16* __restrict__ W2p,   // [LAT/16][HID/32] tiles
                float* __restrict__ acc_g,                // [MTOT][LAT] ksum ws
                float* __restrict__ out) {
    __shared__ __align__(16) unsigned short Xs_s[64 * 256];    //  32 KB
    __shared__ __align__(16) unsigned short Hc_s[64 * 1024];   // 128 KB
    char* XsB = (char*)Xs_s;
    char* HcB = (char*)Hc_s;

    const int tid   = threadIdx.x;
    const int lane  = tid & 63;
    const int wave  = tid >> 6;           // 0..15
    const int wtraj = wave & 1;           // phase-B / state traj group
    const int wgrp  = wave >> 1;          // 0..7: phase-B / state lat slice
    const int q = lane >> 4, l16 = lane & 15;
    const int grow0 = blockIdx.x * RPB;

    // init: t=0 out slice + Xs build (no register state kept)
    #pragma unroll
    for (int mt = 0; mt < 2; ++mt) {
        #pragma unroll
        for (int nt = 0; nt < 2; ++nt) {
            const int traj = wtraj * 32 + nt * 16 + l16;
            const int lat  = wgrp * 32 + mt * 16 + q * 4;
            float4 v = *(const float4*)(fp + (size_t)(grow0 + traj) * LAT + lat);
            *(float4*)(out + ((size_t)(grow0 + traj) * TSTEPS) * LAT + lat) = v;
            st4bf(XsB + addrX(traj, lat * 2), (f32x4){v.x, v.y, v.z, v.w});
        }
    }
    __syncthreads();

    #pragma unroll 1
    for (int step = 0; step < TSTEPS - 1; ++step) {
        const float dt = ts[step + 1] - ts[step];

        #pragma unroll 1
        for (int s = 0; s < 4; ++s) {
            // ================= phase A: Hc = tanh(W1 . Xs^T + b) ==========
            #pragma unroll 1
            for (int h2 = 0; h2 < 2; ++h2) {
                const int hidb = wave * 64 + h2 * 32;      // wave's 32-hid slice
                f32x4 a1[2][4];
                #pragma unroll
                for (int mt = 0; mt < 2; ++mt) {
                    float4 b4 = *(const float4*)(bias1 + hidb + mt * 16 + q * 4);
                    f32x4 bb = (f32x4){b4.x, b4.y, b4.z, b4.w};
                    #pragma unroll
                    for (int nt = 0; nt < 4; ++nt) a1[mt][nt] = bb;
                }
                #pragma unroll
                for (int kk = 0; kk < 8; ++kk) {
                    bf16x8 wf0 = *(const bf16x8*)(W1p +
                        (size_t)(((hidb >> 4) + 0) * 8 + kk) * 512 + lane * 8);
                    bf16x8 wf1 = *(const bf16x8*)(W1p +
                        (size_t)(((hidb >> 4) + 1) * 8 + kk) * 512 + lane * 8);
                    // nt-pair 0,1 (only 2 xf live at a time)
                    {
                        bf16x8 xa = *(const bf16x8*)(XsB + addrX(0 * 16 + l16, kk * 64 + q * 16));
                        bf16x8 xb = *(const bf16x8*)(XsB + addrX(1 * 16 + l16, kk * 64 + q * 16));
                        a1[0][0] = __builtin_amdgcn_mfma_f32_16x16x32_bf16(wf0, xa, a1[0][0], 0, 0, 0);
                        a1[1][0] = __builtin_amdgcn_mfma_f32_16x16x32_bf16(wf1, xa, a1[1][0], 0, 0, 0);
                        a1[0][1] = __builtin_amdgcn_mfma_f32_16x16x32_bf16(wf0, xb, a1[0][1], 0, 0, 0);
                        a1[1][1] = __builtin_amdgcn_mfma_f32_16x16x32_bf16(wf1, xb, a1[1][1], 0, 0, 0);
                    }
                    // nt-pair 2,3
                    {
                        bf16x8 xa = *(const bf16x8*)(XsB + addrX(2 * 16 + l16, kk * 64 + q * 16));
                        bf16x8 xb = *(const bf16x8*)(XsB + addrX(3 * 16 + l16, kk * 64 + q * 16));
                        a1[0][2] = __builtin_amdgcn_mfma_f32_16x16x32_bf16(wf0, xa, a1[0][2], 0, 0, 0);
                        a1[1][2] = __builtin_amdgcn_mfma_f32_16x16x32_bf16(wf1, xa, a1[1][2], 0, 0, 0);
                        a1[0][3] = __builtin_amdgcn_mfma_f32_16x16x32_bf16(wf0, xb, a1[0][3], 0, 0, 0);
                        a1[1][3] = __builtin_amdgcn_mfma_f32_16x16x32_bf16(wf1, xb, a1[1][3], 0, 0, 0);
                    }
                }
                #pragma unroll
                for (int mt = 0; mt < 2; ++mt) {
                    #pragma unroll
                    for (int nt = 0; nt < 4; ++nt) {
                        f32x4 th;
                        #pragma unroll
                        for (int r = 0; r < 4; ++r) {
                            float e  = __builtin_amdgcn_exp2f(a1[mt][nt][r] * C2L2E);
                            float rc = __builtin_amdgcn_rcpf(e + 1.f);
                            th[r] = fmaf(-2.f, rc, 1.f);            // tanh
                        }
                        st4bf(HcB + addrH(nt * 16 + l16,
                                          (hidb + mt * 16 + q * 4) * 2), th);
                    }
                }
            }
            __syncthreads();                // Hc fully written

            // ================= phase B: kacc = W2 . Hc^T ==================
            f32x4 kacc[2][2];
            #pragma unroll
            for (int mt = 0; mt < 2; ++mt) {
                kacc[mt][0] = (f32x4){0.f, 0.f, 0.f, 0.f};
                kacc[mt][1] = (f32x4){0.f, 0.f, 0.f, 0.f};
            }
            #pragma unroll 8
            for (int kk = 0; kk < 32; ++kk) {
                bf16x8 hf0 = *(const bf16x8*)(HcB +
                    addrH(wtraj * 32 + 0 * 16 + l16, kk * 64 + q * 16));
                bf16x8 hf1 = *(const bf16x8*)(HcB +
                    addrH(wtraj * 32 + 1 * 16 + l16, kk * 64 + q * 16));
                #pragma unroll
                for (int mt = 0; mt < 2; ++mt) {
                    bf16x8 wf = *(const bf16x8*)(W2p +
                        (size_t)((wgrp * 2 + mt) * 32 + kk) * 512 + lane * 8);
                    kacc[mt][0] = __builtin_amdgcn_mfma_f32_16x16x32_bf16(wf, hf0, kacc[mt][0], 0, 0, 0);
                    kacc[mt][1] = __builtin_amdgcn_mfma_f32_16x16x32_bf16(wf, hf1, kacc[mt][1], 0, 0, 0);
                }
            }

            // ------- RK4 combine: x from out[:,step,:], ksum in acc_g -------
            #pragma unroll
            for (int mt = 0; mt < 2; ++mt) {
                #pragma unroll
                for (int nt = 0; nt < 2; ++nt) {
                    const int traj = wtraj * 32 + nt * 16 + l16;
                    const int lat  = wgrp * 32 + mt * 16 + q * 4;
                    const size_t rowT = (size_t)(grow0 + traj) * TSTEPS;
                    float* accp = acc_g + (size_t)(grow0 + traj) * LAT + lat;
                    float4 x4 = *(const float4*)(out + (rowT + step) * LAT + lat);
                    f32x4 x  = (f32x4){x4.x, x4.y, x4.z, x4.w};
                    f32x4 kv = kacc[mt][nt];
                    if (s == 0) {
                        *(float4*)accp = make_float4(kv[0], kv[1], kv[2], kv[3]);
                        f32x4 xv = x + (0.5f * dt) * kv;
                        st4bf(XsB + addrX(traj, lat * 2), xv);
                    } else if (s < 3) {
                        const float cw = (s == 2) ? dt : 0.5f * dt;
                        float4 a4 = *(const float4*)accp;
                        *(float4*)accp = make_float4(fmaf(2.f, kv[0], a4.x),
                                                     fmaf(2.f, kv[1], a4.y),
                                                     fmaf(2.f, kv[2], a4.z),
                                                     fmaf(2.f, kv[3], a4.w));
                        f32x4 xv = x + cw * kv;
                        st4bf(XsB + addrX(traj, lat * 2), xv);
                    } else {
                        const float d6 = dt * (1.f / 6.f);
                        float4 a4 = *(const float4*)accp;
                        f32x4 av = (f32x4){a4.x, a4.y, a4.z, a4.w};
                        f32x4 xn = x + d6 * (av + kv);
                        st4bf(XsB + addrX(traj, lat * 2), xn);
                        *(float4*)(out + (rowT + step + 1) * LAT + lat)
                            = make_float4(xn[0], xn[1], xn[2], xn[3]);
                    }
                }
            }
            __syncthreads();   // Xs ready; Hc free for next eval's phase A
        }
    }
}

extern "C" void kernel_launch(void* const* d_in, const int* in_sizes, int n_in,
                              void* d_out, int out_size, void* d_ws, size_t ws_size,
                              hipStream_t stream) {
    (void)in_sizes; (void)n_in; (void)out_size; (void)ws_size;
    const float* fp = (const float*)d_in[0];
    const float* ts = (const float*)d_in[1];
    const float* W1 = (const float*)d_in[2];
    const float* b1 = (const float*)d_in[3];
    const float* W2 = (const float*)d_in[4];
    float* out = (float*)d_out;

    char* ws = (char*)d_ws;
    __hip_bfloat16* W1p = (__hip_bfloat16*)ws;                       // 512 KB
    __hip_bfloat16* W2p = (__hip_bfloat16*)(ws + (size_t)512 * 1024);// 512 KB
    float*          acc = (float*)(ws + (size_t)1024 * 1024);        // 16.8 MB

    // W1: n-dim = HID, k-dim = LAT; src W1 is [LAT][HID] = [K][N]
    pack_kernel<<<(HID * LAT) / 256, 256, 0, stream>>>(W1, W1p, HID, LAT);
    // W2: n-dim = LAT, k-dim = HID; src W2 is [HID][LAT] = [K][N]
    pack_kernel<<<(HID * LAT) / 256, 256, 0, stream>>>(W2, W2p, LAT, HID);

    ode_kernel<<<NBLK, 1024, 0, stream>>>(fp, ts, W1p, b1, W2p, acc, out);
}